// Round 3
// baseline (6489.120 us; speedup 1.0000x reference)
//
#include <hip/hip_runtime.h>
#include <hip/hip_bf16.h>
#include <stdint.h>

#define BATCH 4096
#define UNITS 1024
#define NSTEP 128

typedef __attribute__((ext_vector_type(4))) float f32x4;
typedef __attribute__((ext_vector_type(8))) short s16x8;

__device__ __forceinline__ void gload16(const void* g, void* l) {
  __builtin_amdgcn_global_load_lds(
      (const __attribute__((address_space(1))) unsigned int*)g,
      (__attribute__((address_space(3))) unsigned int*)l, 16, 0, 0);
}

__device__ __forceinline__ void block_barrier() {
  asm volatile("" ::: "memory");
  __builtin_amdgcn_s_barrier();
  asm volatile("" ::: "memory");
}

__device__ __forceinline__ float fsigmoid(float x) {
  return 1.0f / (1.0f + __expf(-x));
}
__device__ __forceinline__ float ftanh(float x) {
  return 1.0f - 2.0f / (__expf(2.0f * x) + 1.0f);
}

// Transpose recurrent_kernel [1024][4096] f32 -> permuted bf16 [4096][1024].
// orig n = g*1024 + u, u = q*64 + wc*16 + ul  ->  n' = q*256 + wc*64 + g*16 + ul
// Rt0 = plain R; Rt1 = R + dense_w (x) kernel (autoregressive fold).
__global__ void prep_weights(const float* __restrict__ R,
                             const float* __restrict__ ker,   // [4096]
                             const float* __restrict__ dw,    // [1024]
                             __hip_bfloat16* __restrict__ Rt0,
                             __hip_bfloat16* __restrict__ Rt1) {
  __shared__ float tile[32][33];
  __shared__ float dws[32];
  const int n0 = blockIdx.x * 32;
  const int k0 = blockIdx.y * 32;
  const int tx = threadIdx.x;       // 0..31
  const int ty = threadIdx.y;       // 0..7
#pragma unroll
  for (int i = 0; i < 4; ++i) {
    int k = ty + i * 8;
    tile[k][tx] = R[(size_t)(k0 + k) * 4096 + n0 + tx];
  }
  if (ty == 0) dws[tx] = dw[k0 + tx];
  __syncthreads();
#pragma unroll
  for (int i = 0; i < 4; ++i) {
    int n = ty + i * 8;
    float v = tile[tx][n];
    int gn = n0 + n, gk = k0 + tx;
    int g = gn >> 10, u = gn & 1023;
    int q = u >> 6, wc = (u >> 4) & 3, ul = u & 15;
    int np = q * 256 + wc * 64 + g * 16 + ul;
    size_t o = (size_t)np * 1024 + gk;
    Rt0[o] = __float2bfloat16(v);
    Rt1[o] = __float2bfloat16(v + dws[tx] * ker[gn]);
  }
}

__global__ void prep_state(const float* __restrict__ feat,   // [4096][512]
                           const float* __restrict__ bias,   // [4096]
                           const float* __restrict__ ker,    // [4096]
                           const float* __restrict__ db,     // [1]
                           float* __restrict__ bias1,
                           __hip_bfloat16* __restrict__ hA,
                           float* __restrict__ c,
                           float* __restrict__ out) {
  const int total = BATCH * UNITS;
  const float dbv = db[0];
  for (int i = blockIdx.x * blockDim.x + threadIdx.x; i < total;
       i += gridDim.x * blockDim.x) {
    int b = i >> 10, u = i & 1023;
    float v = feat[b * 512 + (u & 511)];   // concat([features,features])
    hA[i] = __float2bfloat16(v);
    c[i] = v;
    if (i < 4096) bias1[i] = bias[i] + dbv * ker[i];
    if (i < BATCH * NSTEP) out[i] = dbv;
  }
}

// One LSTM step, 256x256 tile, BK=32, triple-buffered LDS (3 x 32 KB),
// prefetch distance 2, ONE barrier + ONE counted vmcnt(4) per K-tile, two
// setprio-wrapped 16-MFMA clusters with interleaved ds_read / gload_lds.
// Sync invariants: entry vmcnt(4)+barrier => buf[kt%3] fully staged (all
// waves); each wave's lgkmcnt(0) precedes its barrier => no read outlives
// its buffer; stages issued after the barrier target buf[(kt+2)%3] which
// was last read at kt-1.
// LDS layout per buffer: A[256 rows][64 B] + B[256 rows][64 B], 16B slot
// swizzle slot' = k16 ^ (row&3): all 64 lanes of a frag read hit distinct
// 16B units (conflict-free); staging pre-applies the inverse (involution).
__global__ __launch_bounds__(512, 2) void lstm_step(
    const __hip_bfloat16* __restrict__ hin,   // [4096][1024]
    const __hip_bfloat16* __restrict__ Bp,    // permuted Rt [4096][1024]
    const float* __restrict__ biasv,          // [4096] (orig layout)
    float* __restrict__ c,                    // [4096][1024] f32
    __hip_bfloat16* __restrict__ hout,        // [4096][1024]
    const float* __restrict__ dw,             // [1024]
    float* __restrict__ out, int t) {
  extern __shared__ char lds[];   // 98304 bytes = 3 x (16K A + 16K B)
  const int tid = threadIdx.x;
  const int lane = tid & 63;
  const int w = tid >> 6;
  const int l15 = lane & 15;
  const int lhi = lane >> 4;
  const int wr = w >> 2;          // 0..1
  const int wc = w & 3;           // 0..3

  // XCD-aware 4x8 rectangle mapping (as R2)
  const int bi = blockIdx.x;
  const int xcd = bi & 7, slot = bi >> 3;
  const int bx = (xcd & 3) * 4 + (slot & 3);   // 0..15 (batch tiles)
  const int by = (xcd >> 2) * 8 + (slot >> 2); // 0..15 (unit tiles)

  const int ucol = by * 64 + wc * 16 + l15;
  const float dwv = dw[ucol];

  f32x4 acc[8][4];
#pragma unroll
  for (int g = 0; g < 4; ++g) {
    float bg = biasv[g * 1024 + ucol];
#pragma unroll
    for (int m = 0; m < 8; ++m) acc[m][g] = (f32x4){bg, bg, bg, bg};
  }

  const char* Asrc = (const char*)(hin + (size_t)bx * 256 * 1024);
  const char* Bsrc = (const char*)(Bp + (size_t)by * 256 * 1024);
  // staging: inverse-swizzled 16B k-slot within the 64B K-window
  const int ksl = (((lane & 3) ^ ((lane >> 2) & 3)) << 4);
  // read-side swizzled slot byte (row&3 == l15&3 for all frags)
  const int sl = ((lhi ^ (l15 & 3)) << 4);
  const int vA = wr * 8192 + l15 * 64 + sl;    // + m*1024 within A buf
  const int vB = wc * 4096 + l15 * 64 + sl;    // + g*1024 within B buf

  auto STAGE_A = [&](int kt, char* dst) {
#pragma unroll
    for (int i = 0; i < 2; ++i) {
      int row = w * 32 + i * 16 + (lane >> 2);       // local row 0..255
      gload16(Asrc + (size_t)row * 2048 + kt * 64 + ksl,
              dst + (w * 2 + i) * 1024);
    }
  };
  auto STAGE_B = [&](int kt, char* dst) {
#pragma unroll
    for (int i = 0; i < 2; ++i) {
      int row = w * 32 + i * 16 + (lane >> 2);
      gload16(Bsrc + (size_t)row * 2048 + kt * 64 + ksl,
              dst + 16384 + (w * 2 + i) * 1024);
    }
  };

  STAGE_A(0, lds);          STAGE_B(0, lds);
  STAGE_A(1, lds + 32768);  STAGE_B(1, lds + 32768);

  int j2 = 0, js = 2;   // kt%3, (kt+2)%3
  for (int kt = 0; kt < 32; ++kt) {
    if (kt < 31) asm volatile("s_waitcnt vmcnt(4)" ::: "memory");
    else         asm volatile("s_waitcnt vmcnt(0)" ::: "memory");
    block_barrier();
    const char* Ab = lds + j2 * 32768;
    const char* Bb = Ab + 16384;
    char* Sd = lds + js * 32768;

    s16x8 a0[4], a1[4], b0[4];
#pragma unroll
    for (int m = 0; m < 4; ++m) a0[m] = *(const s16x8*)(Ab + vA + m * 1024);
#pragma unroll
    for (int g = 0; g < 4; ++g) b0[g] = *(const s16x8*)(Bb + vB + g * 1024);
    if (kt < 30) STAGE_A(kt + 2, Sd);
#pragma unroll
    for (int m = 0; m < 4; ++m) a1[m] = *(const s16x8*)(Ab + vA + (m + 4) * 1024);
    if (kt < 30) STAGE_B(kt + 2, Sd);

    asm volatile("s_waitcnt lgkmcnt(4)" ::: "memory");  // a0,b0 landed
    __builtin_amdgcn_sched_barrier(0);
    __builtin_amdgcn_s_setprio(1);
#pragma unroll
    for (int m = 0; m < 4; ++m)
#pragma unroll
      for (int g = 0; g < 4; ++g)
        acc[m][g] = __builtin_amdgcn_mfma_f32_16x16x32_bf16(a0[m], b0[g],
                                                            acc[m][g], 0, 0, 0);
    __builtin_amdgcn_s_setprio(0);

    asm volatile("s_waitcnt lgkmcnt(0)" ::: "memory");  // a1 landed
    __builtin_amdgcn_sched_barrier(0);
    __builtin_amdgcn_s_setprio(1);
#pragma unroll
    for (int m = 0; m < 4; ++m)
#pragma unroll
      for (int g = 0; g < 4; ++g)
        acc[m + 4][g] = __builtin_amdgcn_mfma_f32_16x16x32_bf16(a1[m], b0[g],
                                                                acc[m + 4][g], 0, 0, 0);
    __builtin_amdgcn_s_setprio(0);

    j2 = (j2 == 2) ? 0 : j2 + 1;
    js = (js == 2) ? 0 : js + 1;
  }

  // ---- epilogue: gates, c/h update, fused pred partial-dot
#pragma unroll
  for (int m = 0; m < 8; ++m) {
#pragma unroll
    for (int j = 0; j < 4; ++j) {
      int b = bx * 256 + wr * 128 + m * 16 + lhi * 4 + j;
      size_t ci = (size_t)b * 1024 + ucol;
      float zi = acc[m][0][j], zf = acc[m][1][j];
      float zg = acc[m][2][j], zo = acc[m][3][j];
      float ig = fsigmoid(zi), fg = fsigmoid(zf);
      float gg = ftanh(zg), og = fsigmoid(zo);
      float cn = fg * c[ci] + ig * gg;
      c[ci] = cn;
      float hn = og * ftanh(cn);
      hout[ci] = __float2bfloat16(hn);
      float p = hn * dwv;
      p += __shfl_xor(p, 1);
      p += __shfl_xor(p, 2);
      p += __shfl_xor(p, 4);
      p += __shfl_xor(p, 8);
      if (l15 == 0) atomicAdd(&out[(size_t)b * NSTEP + t], p);
    }
  }
}

extern "C" void kernel_launch(void* const* d_in, const int* in_sizes, int n_in,
                              void* d_out, int out_size, void* d_ws, size_t ws_size,
                              hipStream_t stream) {
  const float* feat = (const float*)d_in[0];  // [4096][512]
  const float* ker  = (const float*)d_in[1];  // [1][4096]
  const float* R    = (const float*)d_in[2];  // [1024][4096]
  const float* bias = (const float*)d_in[3];  // [4096]
  const float* dw   = (const float*)d_in[4];  // [1024][1]
  const float* db   = (const float*)d_in[5];  // [1]
  float* out = (float*)d_out;

  char* ws = (char*)d_ws;
  const size_t MB = 1024 * 1024;
  __hip_bfloat16* Rt0 = (__hip_bfloat16*)(ws);            // 8 MB (permuted)
  __hip_bfloat16* Rt1 = (__hip_bfloat16*)(ws + 8 * MB);   // 8 MB (permuted+fold)
  float* bias1 = (float*)(ws + 16 * MB);                  // 16 KB
  __hip_bfloat16* hA = (__hip_bfloat16*)(ws + 16 * MB + 65536);  // 8 MB
  __hip_bfloat16* hB = (__hip_bfloat16*)(ws + 24 * MB + 65536);  // 8 MB
  float* cbuf = (float*)(ws + 32 * MB + 65536);           // 16 MB

  hipFuncSetAttribute((const void*)lstm_step,
                      hipFuncAttributeMaxDynamicSharedMemorySize, 98304);

  prep_weights<<<dim3(128, 32), dim3(32, 8), 0, stream>>>(R, ker, dw, Rt0, Rt1);
  prep_state<<<4096, 256, 0, stream>>>(feat, bias, ker, db, bias1, hA, cbuf, out);

  for (int t = 0; t < NSTEP; ++t) {
    const __hip_bfloat16* hin = (t & 1) ? hB : hA;
    __hip_bfloat16* hout = (t & 1) ? hA : hB;
    lstm_step<<<256, 512, 98304, stream>>>(
        hin, (t == 0) ? Rt0 : Rt1, (t == 0) ? bias : bias1, cbuf, hout, dw, out, t);
  }
}

// Round 4
// 6111.650 us; speedup vs baseline: 1.0618x; 1.0618x over previous
//
#include <hip/hip_runtime.h>
#include <hip/hip_bf16.h>
#include <stdint.h>

#define BATCH 4096
#define UNITS 1024
#define NSTEP 128

typedef __attribute__((ext_vector_type(4))) float f32x4;
typedef __attribute__((ext_vector_type(8))) short s16x8;

__device__ __forceinline__ void gload16(const void* g, void* l) {
  __builtin_amdgcn_global_load_lds(
      (const __attribute__((address_space(1))) unsigned int*)g,
      (__attribute__((address_space(3))) unsigned int*)l, 16, 0, 0);
}

__device__ __forceinline__ void block_barrier() {
  asm volatile("" ::: "memory");
  __builtin_amdgcn_s_barrier();
  asm volatile("" ::: "memory");
}

__device__ __forceinline__ float fsigmoid(float x) {
  return 1.0f / (1.0f + __expf(-x));
}
__device__ __forceinline__ float ftanh(float x) {
  return 1.0f - 2.0f / (__expf(2.0f * x) + 1.0f);
}

// Transpose recurrent_kernel [1024][4096] f32 -> permuted bf16 [4096][1024].
// orig n = g*1024 + u, u = q*64 + wc*16 + ul
//   -> n' = q*256 + (g>>1)*128 + wc*32 + (g&1)*16 + ul
// so each 256-row B tile splits into two CONTIGUOUS 128-row halves by
// gate-pair (g01 / g23) — the unit of staging — and each wave's gate rows
// stay lane-local for the fused epilogue.
// Rt0 = plain R; Rt1 = R + dense_w (x) kernel (autoregressive fold).
__global__ void prep_weights(const float* __restrict__ R,
                             const float* __restrict__ ker,   // [4096]
                             const float* __restrict__ dw,    // [1024]
                             __hip_bfloat16* __restrict__ Rt0,
                             __hip_bfloat16* __restrict__ Rt1) {
  __shared__ float tile[32][33];
  __shared__ float dws[32];
  const int n0 = blockIdx.x * 32;
  const int k0 = blockIdx.y * 32;
  const int tx = threadIdx.x;       // 0..31
  const int ty = threadIdx.y;       // 0..7
#pragma unroll
  for (int i = 0; i < 4; ++i) {
    int k = ty + i * 8;
    tile[k][tx] = R[(size_t)(k0 + k) * 4096 + n0 + tx];
  }
  if (ty == 0) dws[tx] = dw[k0 + tx];
  __syncthreads();
#pragma unroll
  for (int i = 0; i < 4; ++i) {
    int n = ty + i * 8;
    float v = tile[tx][n];
    int gn = n0 + n, gk = k0 + tx;
    int g = gn >> 10, u = gn & 1023;
    int q = u >> 6, wc = (u >> 4) & 3, ul = u & 15;
    int np = q * 256 + (g >> 1) * 128 + wc * 32 + (g & 1) * 16 + ul;
    size_t o = (size_t)np * 1024 + gk;
    Rt0[o] = __float2bfloat16(v);
    Rt1[o] = __float2bfloat16(v + dws[tx] * ker[gn]);
  }
}

__global__ void prep_state(const float* __restrict__ feat,   // [4096][512]
                           const float* __restrict__ bias,   // [4096]
                           const float* __restrict__ ker,    // [4096]
                           const float* __restrict__ db,     // [1]
                           float* __restrict__ bias1,
                           __hip_bfloat16* __restrict__ hA,
                           float* __restrict__ c,
                           float* __restrict__ out) {
  const int total = BATCH * UNITS;
  const float dbv = db[0];
  for (int i = blockIdx.x * blockDim.x + threadIdx.x; i < total;
       i += gridDim.x * blockDim.x) {
    int b = i >> 10, u = i & 1023;
    float v = feat[b * 512 + (u & 511)];   // concat([features,features])
    hA[i] = __float2bfloat16(v);
    c[i] = v;
    if (i < 4096) bias1[i] = bias[i] + dbv * ker[i];
    if (i < BATCH * NSTEP) out[i] = dbv;
  }
}

// One LSTM step, 256x256 tile, BK=64, 8 waves (2M x 4N), 4 fine phases per
// K-tile (16 MFMA each), one half-tile staged per phase, uniform counted
// vmcnt(4) waits (4 loads always in flight, never 0 in steady state).
//
// Per-tile phase plan (quadrants of the wave's 128x64 output):
//   P1: wait h1,h2 -> read A-lo(8)+B-lo(4); stage h1'(A-lo);  MFMA m0-3 x g0-1
//   P2: wait h3    -> read B-hi(4);         stage h2'(B-lo);  MFMA m0-3 x g2-3
//   P3: wait h4    -> read A-hi(8);         stage h3'(B-hi);  MFMA m4-7 x g2-3
//   P4: (regs only)                         stage h4'(A-hi);  MFMA m4-7 x g0-1
// Invariant: each wave's vmcnt(N) + the following barrier guarantee (by
// symmetric per-wave issue counts) that the half about to be ds_read has
// been fully staged by ALL waves. Each wave's lgkmcnt(0) precedes its next
// barrier, so no read outlives its buffer; stages after a phase barrier
// target the buffer whose reads finished last iteration.
// Swizzle: verified R1/R2 scheme — 128 B rows, byte ^= ((row&7)<<4),
// inverse pre-applied on the global source (involution, 0 conflicts).
__global__ __launch_bounds__(512, 2) void lstm_step(
    const __hip_bfloat16* __restrict__ hin,   // [4096][1024]
    const __hip_bfloat16* __restrict__ Bp,    // permuted Rt [4096][1024]
    const float* __restrict__ biasv,          // [4096] (orig layout)
    float* __restrict__ c,                    // [4096][1024] f32
    __hip_bfloat16* __restrict__ hout,        // [4096][1024]
    const float* __restrict__ dw,             // [1024]
    float* __restrict__ out, int t) {
  extern __shared__ char lds[];   // 131072 = 2 buf x (A 32K + B 32K)
  const int tid = threadIdx.x;
  const int lane = tid & 63;
  const int w = tid >> 6;
  const int l15 = lane & 15;
  const int lhi = lane >> 4;
  const int wr = w >> 2;          // 0..1
  const int wc = w & 3;           // 0..3

  // XCD-aware 4x8 rectangle mapping
  const int bi = blockIdx.x;
  const int xcd = bi & 7, slot = bi >> 3;
  const int bx = (xcd & 3) * 4 + (slot & 3);   // 0..15 (batch tiles)
  const int by = (xcd >> 2) * 8 + (slot >> 2); // 0..15 (unit tiles)

  const int ucol = by * 64 + wc * 16 + l15;
  const float dwv = dw[ucol];

  f32x4 acc[8][4];
#pragma unroll
  for (int g = 0; g < 4; ++g) {
    float bg = biasv[g * 1024 + ucol];
#pragma unroll
    for (int m = 0; m < 8; ++m) acc[m][g] = (f32x4){bg, bg, bg, bg};
  }

  const char* Asrc = (const char*)(hin + (size_t)bx * 256 * 1024);
  const char* Bsrc = (const char*)(Bp + (size_t)by * 256 * 1024);
  const int swz = (l15 & 7) << 4;   // read-side swizzle (row&7 == l15&7)

  // Stage one 128-row half (16 KB): 2 gload16/thread, linear LDS dest,
  // inverse-swizzled global source.
  auto STAGE = [&](const char* src, int rowoff, int kt, char* dstbase) {
#pragma unroll
    for (int i = 0; i < 2; ++i) {
      int chunk = i * 512 + tid;
      int row = chunk >> 3, s = chunk & 7;
      gload16(src + (size_t)(rowoff + row) * 2048 + kt * 128 +
                  ((s * 16) ^ ((row & 7) << 4)),
              dstbase + i * 8192 + w * 1024 + lane * 16);
    }
  };

  // prologue: tile 0, halves in need-order h1..h4 (8 issues/thread)
  STAGE(Asrc, 0,   0, lds);                    // h1 A-lo
  STAGE(Bsrc, 0,   0, lds + 32768);            // h2 B-lo (gates 0,1)
  STAGE(Bsrc, 128, 0, lds + 32768 + 16384);    // h3 B-hi (gates 2,3)
  STAGE(Asrc, 128, 0, lds + 16384);            // h4 A-hi

  for (int kt = 0; kt < 16; ++kt) {
    const char* Ab = lds + (kt & 1) * 65536;
    const char* Bb = Ab + 32768;
    char* Sd = lds + ((kt + 1) & 1) * 65536;
    const bool pf = (kt < 15);

    s16x8 al[4][2], bl[2][2], bh[2][2], ah[4][2];

    // ---------- P1: needs A-lo (h1) + B-lo (h2)
    asm volatile("s_waitcnt vmcnt(4)" ::: "memory");
    block_barrier();
#pragma unroll
    for (int m = 0; m < 4; ++m) {
      int row = wr * 64 + m * 16 + l15;   // A-lo rows 0..127
#pragma unroll
      for (int kk = 0; kk < 2; ++kk)
        al[m][kk] = *(const s16x8*)(Ab + row * 128 + ((kk * 64 + lhi * 16) ^ swz));
    }
#pragma unroll
    for (int g = 0; g < 2; ++g) {
      int row = wc * 32 + g * 16 + l15;   // B-lo rows 0..127
#pragma unroll
      for (int kk = 0; kk < 2; ++kk)
        bl[g][kk] = *(const s16x8*)(Bb + row * 128 + ((kk * 64 + lhi * 16) ^ swz));
    }
    if (pf) STAGE(Asrc, 0, kt + 1, Sd);                      // h1'
    asm volatile("s_waitcnt lgkmcnt(0)" ::: "memory");
    __builtin_amdgcn_sched_barrier(0);
    __builtin_amdgcn_s_setprio(1);
#pragma unroll
    for (int m = 0; m < 4; ++m)
#pragma unroll
      for (int g = 0; g < 2; ++g)
#pragma unroll
        for (int kk = 0; kk < 2; ++kk)
          acc[m][g] = __builtin_amdgcn_mfma_f32_16x16x32_bf16(
              al[m][kk], bl[g][kk], acc[m][g], 0, 0, 0);
    __builtin_amdgcn_s_setprio(0);

    // ---------- P2: needs B-hi (h3)
    if (pf) asm volatile("s_waitcnt vmcnt(4)" ::: "memory");
    else    asm volatile("s_waitcnt vmcnt(2)" ::: "memory");
    block_barrier();
#pragma unroll
    for (int g = 0; g < 2; ++g) {
      int row = 128 + wc * 32 + g * 16 + l15;   // B-hi rows 128..255
#pragma unroll
      for (int kk = 0; kk < 2; ++kk)
        bh[g][kk] = *(const s16x8*)(Bb + row * 128 + ((kk * 64 + lhi * 16) ^ swz));
    }
    if (pf) STAGE(Bsrc, 0, kt + 1, Sd + 32768);              // h2'
    asm volatile("s_waitcnt lgkmcnt(0)" ::: "memory");
    __builtin_amdgcn_sched_barrier(0);
    __builtin_amdgcn_s_setprio(1);
#pragma unroll
    for (int m = 0; m < 4; ++m)
#pragma unroll
      for (int g = 0; g < 2; ++g)
#pragma unroll
        for (int kk = 0; kk < 2; ++kk)
          acc[m][g + 2] = __builtin_amdgcn_mfma_f32_16x16x32_bf16(
              al[m][kk], bh[g][kk], acc[m][g + 2], 0, 0, 0);
    __builtin_amdgcn_s_setprio(0);

    // ---------- P3: needs A-hi (h4)
    if (pf) asm volatile("s_waitcnt vmcnt(4)" ::: "memory");
    else    asm volatile("s_waitcnt vmcnt(0)" ::: "memory");
    block_barrier();
#pragma unroll
    for (int m = 0; m < 4; ++m) {
      int row = 128 + wr * 64 + m * 16 + l15;   // A-hi rows 128..255
#pragma unroll
      for (int kk = 0; kk < 2; ++kk)
        ah[m][kk] = *(const s16x8*)(Ab + row * 128 + ((kk * 64 + lhi * 16) ^ swz));
    }
    if (pf) STAGE(Bsrc, 128, kt + 1, Sd + 32768 + 16384);    // h3'
    asm volatile("s_waitcnt lgkmcnt(0)" ::: "memory");
    __builtin_amdgcn_sched_barrier(0);
    __builtin_amdgcn_s_setprio(1);
#pragma unroll
    for (int m = 0; m < 4; ++m)
#pragma unroll
      for (int g = 0; g < 2; ++g)
#pragma unroll
        for (int kk = 0; kk < 2; ++kk)
          acc[m + 4][g + 2] = __builtin_amdgcn_mfma_f32_16x16x32_bf16(
              ah[m][kk], bh[g][kk], acc[m + 4][g + 2], 0, 0, 0);
    __builtin_amdgcn_s_setprio(0);

    // ---------- P4: registers only
    if (pf) STAGE(Asrc, 128, kt + 1, Sd + 16384);            // h4'
    __builtin_amdgcn_s_setprio(1);
#pragma unroll
    for (int m = 0; m < 4; ++m)
#pragma unroll
      for (int g = 0; g < 2; ++g)
#pragma unroll
        for (int kk = 0; kk < 2; ++kk)
          acc[m + 4][g] = __builtin_amdgcn_mfma_f32_16x16x32_bf16(
              ah[m][kk], bl[g][kk], acc[m + 4][g], 0, 0, 0);
    __builtin_amdgcn_s_setprio(0);
  }

  // ---- epilogue: gates, c/h update, fused pred partial-dot
  // A row map: row(m) = (m>>2)*128 + wr*64 + (m&3)*16 + l15
#pragma unroll
  for (int m = 0; m < 8; ++m) {
#pragma unroll
    for (int j = 0; j < 4; ++j) {
      int b = bx * 256 + (m >> 2) * 128 + wr * 64 + (m & 3) * 16 + lhi * 4 + j;
      size_t ci = (size_t)b * 1024 + ucol;
      float zi = acc[m][0][j], zf = acc[m][1][j];
      float zg = acc[m][2][j], zo = acc[m][3][j];
      float ig = fsigmoid(zi), fg = fsigmoid(zf);
      float gg = ftanh(zg), og = fsigmoid(zo);
      float cn = fg * c[ci] + ig * gg;
      c[ci] = cn;
      float hn = og * ftanh(cn);
      hout[ci] = __float2bfloat16(hn);
      float p = hn * dwv;
      p += __shfl_xor(p, 1);
      p += __shfl_xor(p, 2);
      p += __shfl_xor(p, 4);
      p += __shfl_xor(p, 8);
      if (l15 == 0) atomicAdd(&out[(size_t)b * NSTEP + t], p);
    }
  }
}

extern "C" void kernel_launch(void* const* d_in, const int* in_sizes, int n_in,
                              void* d_out, int out_size, void* d_ws, size_t ws_size,
                              hipStream_t stream) {
  const float* feat = (const float*)d_in[0];  // [4096][512]
  const float* ker  = (const float*)d_in[1];  // [1][4096]
  const float* R    = (const float*)d_in[2];  // [1024][4096]
  const float* bias = (const float*)d_in[3];  // [4096]
  const float* dw   = (const float*)d_in[4];  // [1024][1]
  const float* db   = (const float*)d_in[5];  // [1]
  float* out = (float*)d_out;

  char* ws = (char*)d_ws;
  const size_t MB = 1024 * 1024;
  __hip_bfloat16* Rt0 = (__hip_bfloat16*)(ws);            // 8 MB (permuted)
  __hip_bfloat16* Rt1 = (__hip_bfloat16*)(ws + 8 * MB);   // 8 MB (permuted+fold)
  float* bias1 = (float*)(ws + 16 * MB);                  // 16 KB
  __hip_bfloat16* hA = (__hip_bfloat16*)(ws + 16 * MB + 65536);  // 8 MB
  __hip_bfloat16* hB = (__hip_bfloat16*)(ws + 24 * MB + 65536);  // 8 MB
  float* cbuf = (float*)(ws + 32 * MB + 65536);           // 16 MB

  hipFuncSetAttribute((const void*)lstm_step,
                      hipFuncAttributeMaxDynamicSharedMemorySize, 131072);

  prep_weights<<<dim3(128, 32), dim3(32, 8), 0, stream>>>(R, ker, dw, Rt0, Rt1);
  prep_state<<<4096, 256, 0, stream>>>(feat, bias, ker, db, bias1, hA, cbuf, out);

  for (int t = 0; t < NSTEP; ++t) {
    const __hip_bfloat16* hin = (t & 1) ? hB : hA;
    __hip_bfloat16* hout = (t & 1) ? hA : hB;
    lstm_step<<<256, 512, 131072, stream>>>(
        hin, (t == 0) ? Rt0 : Rt1, (t == 0) ? bias : bias1, cbuf, hout, dw, out, t);
  }
}